// Round 6
// baseline (341.634 us; speedup 1.0000x reference)
//
#include <hip/hip_runtime.h>

// QuadNeighborhoodEncoderDeepsets on gfx950 — round 9.
// r8 post-mortem: issue-slot-bound (VALU 51% + LDS ~40% + MFMA 22% + barrier
// drains). Two additive cuts on the passing r8 dataflow:
// (1) double-buffered a[] -> ONE barrier/tile. B(t) orders L1w(t,p) < L2r(t,p);
//     reuse ordering: V-L2r(t-1,p^1) < V-B(t) = W-B(t) < W-L1w(t+1,p^1), with
//     compiler's lgkmcnt(0) drain before s_barrier. Distinct buffers (r6's
//     failed aliased-union case does not apply). LDS 50.7KB, 2 blocks = 101KB.
// (2) bias folded into MFMA C-input + weights pre-scaled by 2/ln2 in prep:
//     tanh = exp2, add, rcp, fma (leading fma deleted, 48 fma/lane-tile saved).
// Mean stays the r8 register-space shfl_xor(16/48) routing (passed, verified).

#define HID     256
#define OBSD    54
#define SELFD   18
#define TILE_B  8
#define TILE_R  48            // 8 batches * 6 neighbors
#define LDA     264           // A-tile row stride (shorts), 16B-aligned rows
#define BATCHN  131072
#define NTILES  (BATCHN / TILE_B)
#define GRID_WG 2048
#define TANH_K  2.8853900817779268f   // 2/ln2

typedef __attribute__((ext_vector_type(8))) short bf16x8;   // 4 VGPRs
typedef __attribute__((ext_vector_type(4))) float f32x4;

// pack two f32 -> one dword of 2 bf16 (RNE), single VALU op
__device__ __forceinline__ unsigned cvt_pk_bf16(float lo, float hi) {
    unsigned r;
    asm("v_cvt_pk_bf16_f32 %0, %1, %2" : "=v"(r) : "v"(lo), "v"(hi));
    return r;
}

// z already = (x+b)*2/ln2 (weights+bias pre-scaled):
// tanh = 1 - 2/(2^z + 1): exp2 + add + rcp + fma (2 VALU + 2 trans)
__device__ __forceinline__ float tanh_z(float z) {
    float t = __builtin_amdgcn_exp2f(z);
    return 1.0f - 2.0f * __builtin_amdgcn_rcpf(t + 1.0f);
}

// fp32 -> bf16 bits (RNE) — prep kernel only
__device__ __forceinline__ unsigned bfbits(float f) {
    unsigned u = __float_as_uint(f);
    u += 0x7fffu + ((u >> 16) & 1u);
    return u >> 16;
}

// Weights pre-scaled by TANH_K so the MFMA result is already exp2-ready:
// w2t[n][k] = bf16(K * W2[k][n])  (256x256)
// w1t[n][k] = k<6 ? bf16(K * W1[k][n]) : 0   (256x32, K zero-padded)
__global__ void prep(const float* __restrict__ W1, const float* __restrict__ W2,
                     short* __restrict__ w1t, short* __restrict__ w2t) {
    int idx = blockIdx.x * 256 + threadIdx.x;
    if (idx < 65536) {
        int n = idx >> 8, k = idx & 255;
        w2t[idx] = (short)bfbits(W2[k * HID + n] * TANH_K);
    } else {
        int j = idx - 65536;
        int n = j >> 5, k = j & 31;
        w1t[j] = (k < 6) ? (short)bfbits(W1[k * HID + n] * TANH_K) : (short)0;
    }
}

__global__ __launch_bounds__(512, 4) void qenc_main(
        const float* __restrict__ obs,
        const short* __restrict__ w1t,
        const float* __restrict__ b1,
        const short* __restrict__ w2t,
        const float* __restrict__ b2,
        float* __restrict__ out)
{
    __shared__ short a2[2][TILE_R * LDA];     // 2 x 25344 B : bf16 h1 dbuf

    const int tid  = threadIdx.x;
    const int wave = tid >> 6;        // 0..7
    const int lane = tid & 63;
    const int q    = lane >> 4;
    const int c16  = lane & 15;
    const int colbase = wave * 32;    // this wave's 32-column slice

    // ---- persistent fragments / constants (loaded once per workgroup) ----
    // B layout for 16x16x32: lane holds B[k=q*8+j][n=lane&15].
    bf16x8 Bf[8][2];                  // K-scaled W2^T slice: 64 regs
    #pragma unroll
    for (int kk = 0; kk < 8; ++kk)
        #pragma unroll
        for (int ct = 0; ct < 2; ++ct)
            Bf[kk][ct] = *(const bf16x8*)
                (w2t + (colbase + ct * 16 + c16) * HID + kk * 32 + q * 8);

    // K-scaled W1^T frags (A-operand of swapped layer-1 MFMA): 8 regs
    bf16x8 B1f[2];
    #pragma unroll
    for (int ct = 0; ct < 2; ++ct)
        B1f[ct] = *(const bf16x8*)(w1t + (colbase + ct * 16 + c16) * 32 + q * 8);

    // biases, pre-scaled by K, used as MFMA C-inputs.
    // layer-1 swapped-MFMA: lane's output cols are colbase + ct*16 + q*4 + g
    float b1s[2][4];
    #pragma unroll
    for (int ct = 0; ct < 2; ++ct)
        #pragma unroll
        for (int g = 0; g < 4; ++g)
            b1s[ct][g] = b1[colbase + ct * 16 + q * 4 + g] * TANH_K;
    // layer-2: lane's 4 acc rows share col = colbase + ct*16 + c16
    float b2s[2];
    #pragma unroll
    for (int ct = 0; ct < 2; ++ct)
        b2s[ct] = b2[colbase + ct * 16 + c16] * TANH_K;

    // per-lane x source offsets (constant across tiles): row = rt*16+c16
    int soff[3];
    #pragma unroll
    for (int rt = 0; rt < 3; ++rt) {
        int row = rt * 16 + c16;
        soff[rt] = (row / 6) * OBSD + SELFD + (row % 6) * 6;
    }

    // register-mean routing (q-only, precomputed):
    // lane q owns batches blA = {0,3,4,7}[q] and blB = {5,6,1,2}[q]
    const int blA = 2 * q + (q & 1);              // 0,3,4,7
    const int blB = (q < 2) ? (q + 5) : (q - 1);  // 5,6,1,2
    const bool isq0 = (q == 0), isq1 = (q == 1), isq2 = (q == 2);

    int pb = 0;
    for (int tile = blockIdx.x; tile < NTILES; tile += GRID_WG) {
        const size_t obase = (size_t)tile * (TILE_B * OBSD);
        short* __restrict__ a = a2[pb];

        // ---- layer 1: h1 = tanh(x @ W1 + b1), swapped operands ----
        // mfma(K*W1T-as-A, x-as-B, C=K*b1): lane holds rows = rt*16+c16,
        // cols = colbase + ct*16 + q*4 + g  (4 consecutive -> 8B store)
        #pragma unroll
        for (int rt = 0; rt < 3; ++rt) {
            // every lane loads its row's 6 floats (q/wave-redundant, L1-hot);
            // k>=6 multiplies w1t's zero rows -> contributes exactly zero.
            const float* src = obs + obase + soff[rt];
            float2 f0 = *(const float2*)(src);
            float2 f1 = *(const float2*)(src + 2);
            float2 f2 = *(const float2*)(src + 4);
            union { unsigned w[4]; bf16x8 v; } xf;
            xf.w[0] = cvt_pk_bf16(f0.x, f0.y);
            xf.w[1] = cvt_pk_bf16(f1.x, f1.y);
            xf.w[2] = cvt_pk_bf16(f2.x, f2.y);
            xf.w[3] = 0u;
            #pragma unroll
            for (int ct = 0; ct < 2; ++ct) {
                f32x4 c = __builtin_amdgcn_mfma_f32_16x16x32_bf16(
                    B1f[ct], xf.v,
                    (f32x4){b1s[ct][0], b1s[ct][1], b1s[ct][2], b1s[ct][3]},
                    0, 0, 0);
                float t0 = tanh_z(c[0]);
                float t1 = tanh_z(c[1]);
                float t2 = tanh_z(c[2]);
                float t3 = tanh_z(c[3]);
                uint2 dd;
                dd.x = cvt_pk_bf16(t0, t1);
                dd.y = cvt_pk_bf16(t2, t3);
                // row-major A-tile, 4 consecutive cols -> one 8B store
                *(uint2*)&a[(rt * 16 + c16) * LDA + colbase + ct * 16 + q * 4] = dd;
            }
        }
        __syncthreads();   // L1w(t,pb) < L2r(t,pb); also orders prior-tile
                           // L2r(t-1,pb^1) < upcoming L1w(t+1,pb^1)

        // ---- layer 2: (48x256)@(256x32 slice), B in regs, C-init = bias ----
        f32x4 acc[3][2];
        #pragma unroll
        for (int rt = 0; rt < 3; ++rt)
            #pragma unroll
            for (int ct = 0; ct < 2; ++ct)
                acc[rt][ct] = (f32x4){b2s[ct], b2s[ct], b2s[ct], b2s[ct]};

        #pragma unroll
        for (int kk = 0; kk < 8; ++kk) {
            bf16x8 Af[3];   // A layout: lane holds A[m=lane&15][k=q*8+j]
            #pragma unroll
            for (int rt = 0; rt < 3; ++rt)
                Af[rt] = *(const bf16x8*)&a[(rt * 16 + c16) * LDA + kk * 32 + q * 8];
            #pragma unroll
            for (int rt = 0; rt < 3; ++rt)
                #pragma unroll
                for (int ct = 0; ct < 2; ++ct)
                    acc[rt][ct] = __builtin_amdgcn_mfma_f32_16x16x32_bf16(
                        Af[rt], Bf[kk][ct], acc[rt][ct], 0, 0, 0);
        }

        // ---- fused epilogue: tanh -> register-space neighbor mean ----
        // C layout: col = colbase + ct*16 + c16, row = rt*16 + q*4 + g.
        //   s[rt] = t0+t1, u[rt] = t2+t3, f[rt] = s+u
        //   q0: A=f0(bl0) B=s1(bl2) C=u1(bl3) D=f2(bl5)
        //   q1: A=s0(bl0) B=u0(bl1) C=f1(bl3) D=f2(bl6)
        //   q2: A=f0(bl1) B=f1(bl4) C=s2(bl6) D=u2(bl7)
        //   q3: A=f0(bl2) B=s1(bl4) C=u1(bl5) D=f2(bl7)
        // Pairs (xor16): (q0,q1)->{bl0,bl3}, (q2,q3)->{bl4,bl7}
        // Pairs (xor48): (q1,q2)->{bl1,bl6}, (q3,q0)->{bl2,bl5}
        const int b0 = tile * TILE_B;
        #pragma unroll
        for (int ct = 0; ct < 2; ++ct) {
            const int col = colbase + ct * 16 + c16;
            float s[3], uu[3], f[3];
            #pragma unroll
            for (int rt = 0; rt < 3; ++rt) {
                float t0 = tanh_z(acc[rt][ct][0]);
                float t1 = tanh_z(acc[rt][ct][1]);
                float t2 = tanh_z(acc[rt][ct][2]);
                float t3 = tanh_z(acc[rt][ct][3]);
                s[rt] = t0 + t1; uu[rt] = t2 + t3; f[rt] = s[rt] + uu[rt];
            }
            float A = isq1 ? s[0] : f[0];
            float B = isq1 ? uu[0] : (isq2 ? f[1] : s[1]);
            float C = isq2 ? s[2] : (isq1 ? f[1] : uu[1]);
            float D = isq2 ? uu[2] : f[2];
            // X1 payload: q0->C, q1->A, q2->D, q3->B   (xor 16)
            float p1 = isq0 ? C : (isq1 ? A : (isq2 ? D : B));
            // X2 payload: q0,q1->B ; q2,q3->C          (xor 48)
            float p2 = (q < 2) ? B : C;
            float r1 = __shfl_xor(p1, 16);
            float r2 = __shfl_xor(p2, 48);
            // owned sums: q0:A+q1.A(bl0)  q1:C+q0.C(bl3)
            //             q2:B+q3.B(bl4)  q3:D+q2.D(bl7)
            float own1 = (isq0 ? A : (isq1 ? C : (isq2 ? B : D))) + r1;
            // owned sums: q0:D+q3.C(bl5)  q1:D+q2.C(bl6)
            //             q2:A+q1.B(bl1)  q3:A+q0.B(bl2)
            float own2 = ((q < 2) ? D : A) + r2;
            out[(size_t)(b0 + blA) * HID + col] = own1 * (1.0f / 6.0f);
            out[(size_t)(b0 + blB) * HID + col] = own2 * (1.0f / 6.0f);
        }
        pb ^= 1;   // no end-of-tile barrier: next tile writes the other buffer
    }
}

extern "C" void kernel_launch(void* const* d_in, const int* in_sizes, int n_in,
                              void* d_out, int out_size, void* d_ws, size_t ws_size,
                              hipStream_t stream) {
    // inputs: 0 self_obs (unused), 1 obs, 2 W1, 3 b1, 4 W2, 5 b2, 6/7 scalars
    const float* obs = (const float*)d_in[1];
    const float* W1  = (const float*)d_in[2];
    const float* b1  = (const float*)d_in[3];
    const float* W2  = (const float*)d_in[4];
    const float* b2  = (const float*)d_in[5];
    float* outp = (float*)d_out;

    short* w2t = (short*)d_ws;                       // 131072 B
    short* w1t = (short*)((char*)d_ws + 131072);     // 16384 B

    prep<<<288, 256, 0, stream>>>(W1, W2, w1t, w2t);
    qenc_main<<<GRID_WG, 512, 0, stream>>>(obs, w1t, b1, w2t, b2, outp);
}